// Round 1
// baseline (162.440 us; speedup 1.0000x reference)
//
#include <hip/hip_runtime.h>
#include <math.h>

// KLDiv symmetric loss with closed-form soft targets.
// probs3[i,k] = e^10/D_i if labels[k]==labels[i] else 1/D_i,
//   D_i = cnt[l_i]*e^10 + (N - cnt[l_i])   (cnt = class histogram of labels)
// loss = (2H - S1 - S2) / (2N), where
//   H    = sum_{i,k} probs3[i,k] * log probs3[i,k]          (closed form, O(classes))
//   S1   = sum_i  w_i (rowsum1_i - N*lse1_i) + (e^10-1) w_i (matchsum1_i - cnt_i*lse1_i)
//   S2   = sum_k  (wsum2_k - lse2_k*W) + (e^10-1) w_k (matchsum2_k - cnt_k*lse2_k)
//   w_i = 1/D_i,  W = sum_i w_i = sum_c cnt[c]/D_c
// Each pred matrix is streamed exactly once (memory-bound: 537 MB total).

constexpr int N_ = 8192;
constexpr int NCLS = 100;
constexpr float E10F = 22026.465794806718f;  // exp(10)

__global__ void hist_kernel(const int* __restrict__ labels,
                            int* __restrict__ counts,
                            float* __restrict__ wcls,
                            float* __restrict__ Wout) {
    __shared__ int cnt[NCLS];
    int tid = threadIdx.x;
    if (tid < NCLS) cnt[tid] = 0;
    __syncthreads();
    for (int i = tid; i < N_; i += blockDim.x)
        atomicAdd(&cnt[labels[i]], 1);
    __syncthreads();
    if (tid < NCLS) {
        int c = cnt[tid];
        counts[tid] = c;
        float D = (float)c * E10F + (float)(N_ - c);
        wcls[tid] = 1.0f / D;
    }
    __syncthreads();
    if (tid == 0) {
        double W = 0.0;
        const double e10 = 22026.465794806718;
        for (int c = 0; c < NCLS; ++c) {
            double cc = (double)cnt[c];
            double D = cc * e10 + ((double)N_ - cc);
            W += cc / D;
        }
        Wout[0] = (float)W;
    }
}

__global__ void warr_kernel(const int* __restrict__ labels,
                            const float* __restrict__ wcls,
                            float* __restrict__ warr) {
    int i = blockIdx.x * blockDim.x + threadIdx.x;
    if (i < N_) warr[i] = wcls[labels[i]];
}

// One block (256 threads) per row. Streams the row once with float4 loads,
// maintaining online logsumexp + (weighted) row sum + matched-column sum.
template <bool SECOND>
__launch_bounds__(256)
__global__ void row_kernel(const float* __restrict__ pred,
                           const int* __restrict__ labels,
                           const float* __restrict__ warr,
                           const int* __restrict__ counts,
                           const float* __restrict__ wcls,
                           const float* __restrict__ Wptr,
                           float* __restrict__ contrib) {
    const int r = blockIdx.x;
    const int tid = threadIdx.x;
    const float4* row4 = reinterpret_cast<const float4*>(pred + (size_t)r * N_);
    const int4* lab4 = reinterpret_cast<const int4*>(labels);
    const float4* w4p = reinterpret_cast<const float4*>(warr);
    const int rowlab = labels[r];

    float m = -1e30f;   // running max (online lse)
    float s = 0.0f;     // running sum of exp(v - m)
    float sum = 0.0f;   // rowsum (pred1) or w-weighted rowsum (pred2)
    float msum = 0.0f;  // sum over label-matching columns

#pragma unroll
    for (int it = 0; it < 8; ++it) {
        const int idx = it * 256 + tid;           // 2048 float4's per row
        float4 v = row4[idx];
        int4 lb = lab4[idx];

        float vmax = fmaxf(fmaxf(v.x, v.y), fmaxf(v.z, v.w));
        float nm = fmaxf(m, vmax);
        s = s * __expf(m - nm) + __expf(v.x - nm) + __expf(v.y - nm) +
            __expf(v.z - nm) + __expf(v.w - nm);
        m = nm;

        if (SECOND) {
            float4 w = w4p[idx];
            sum = fmaf(v.x, w.x, fmaf(v.y, w.y, fmaf(v.z, w.z, fmaf(v.w, w.w, sum))));
        } else {
            sum += (v.x + v.y) + (v.z + v.w);
        }
        msum += (lb.x == rowlab ? v.x : 0.0f) + (lb.y == rowlab ? v.y : 0.0f) +
                (lb.z == rowlab ? v.z : 0.0f) + (lb.w == rowlab ? v.w : 0.0f);
    }

    // 64-lane butterfly reduce: (m,s) lse-merge + plain sums
#pragma unroll
    for (int mask = 32; mask >= 1; mask >>= 1) {
        float om = __shfl_xor(m, mask, 64);
        float os = __shfl_xor(s, mask, 64);
        float nm = fmaxf(m, om);
        s = s * __expf(m - nm) + os * __expf(om - nm);
        m = nm;
        sum += __shfl_xor(sum, mask, 64);
        msum += __shfl_xor(msum, mask, 64);
    }

    __shared__ float redm[4], reds[4], redsum[4], redmsum[4];
    const int wave = tid >> 6;
    if ((tid & 63) == 0) {
        redm[wave] = m; reds[wave] = s; redsum[wave] = sum; redmsum[wave] = msum;
    }
    __syncthreads();
    if (tid == 0) {
        float M = redm[0], S = reds[0], SU = redsum[0], MS = redmsum[0];
#pragma unroll
        for (int wv = 1; wv < 4; ++wv) {
            float om = redm[wv], os = reds[wv];
            float nm = fmaxf(M, om);
            S = S * __expf(M - nm) + os * __expf(om - nm);
            M = nm;
            SU += redsum[wv];
            MS += redmsum[wv];
        }
        float lse = logf(S) + M;
        int cnt = counts[rowlab];
        float w = wcls[rowlab];
        float c;
        if (!SECOND) {
            c = w * (SU - (float)N_ * lse) + (E10F - 1.0f) * w * (MS - (float)cnt * lse);
        } else {
            float W = Wptr[0];
            c = (SU - lse * W) + (E10F - 1.0f) * w * (MS - (float)cnt * lse);
        }
        contrib[r] = c;
    }
}

__global__ void final_kernel(const int* __restrict__ counts,
                             const float* __restrict__ contrib1,
                             const float* __restrict__ contrib2,
                             float* __restrict__ out) {
    __shared__ double red[256];
    int tid = threadIdx.x;
    double acc = 0.0;
    for (int i = tid; i < N_; i += 256)
        acc += (double)contrib1[i] + (double)contrib2[i];
    red[tid] = acc;
    __syncthreads();
    for (int st = 128; st > 0; st >>= 1) {
        if (tid < st) red[tid] += red[tid + st];
        __syncthreads();
    }
    if (tid == 0) {
        const double e10 = 22026.465794806718;
        double H = 0.0;
        for (int c = 0; c < NCLS; ++c) {
            double cc = (double)counts[c];
            double D = cc * e10 + ((double)N_ - cc);
            double logD = log(D);
            // cc rows of this class; each: cc matches at p=e10/D, (N-cc) at p=1/D
            H += cc * (cc * (e10 / D) * (10.0 - logD) +
                       ((double)N_ - cc) * (1.0 / D) * (-logD));
        }
        double S = red[0];  // S1 + S2
        out[0] = (float)((2.0 * H - S) / (2.0 * (double)N_));
    }
}

extern "C" void kernel_launch(void* const* d_in, const int* in_sizes, int n_in,
                              void* d_out, int out_size, void* d_ws, size_t ws_size,
                              hipStream_t stream) {
    const float* pred1 = (const float*)d_in[0];
    const float* pred2 = (const float*)d_in[1];
    const int* labels = (const int*)d_in[2];
    float* out = (float*)d_out;

    float* wsf = (float*)d_ws;
    int* wsi = (int*)d_ws;
    int* counts    = wsi;          // [0..127]
    float* wcls    = wsf + 128;    // [128..255]
    float* Wptr    = wsf + 256;    // scalar W
    float* warr    = wsf + 512;    // [512 .. 512+8191]
    float* contrib1 = wsf + 8704;  // [8704 .. +8191]
    float* contrib2 = wsf + 16896; // [16896 .. +8191]

    hist_kernel<<<1, 256, 0, stream>>>(labels, counts, wcls, Wptr);
    warr_kernel<<<N_ / 256, 256, 0, stream>>>(labels, wcls, warr);
    row_kernel<false><<<N_, 256, 0, stream>>>(pred1, labels, warr, counts, wcls, Wptr, contrib1);
    row_kernel<true><<<N_, 256, 0, stream>>>(pred2, labels, warr, counts, wcls, Wptr, contrib2);
    final_kernel<<<1, 256, 0, stream>>>(counts, contrib1, contrib2, out);
}